// Round 8
// baseline (110.450 us; speedup 1.0000x reference)
//
#include <hip/hip_runtime.h>

// ExemplarNoAttention: logits[b,c] = log( sum_{e: label[e]==c} exp(-beta*d2[b,e]) + eps )
// d2[b,e] = ||x_b||^2 + ||e_e||^2 - 2<x_b,e_e>, clamped >= 0; beta = softplus(beta_raw).
//
// Round 8 = R6 base (best measured) with the staging path rebuilt:
//  (a) Ah staged via __builtin_amdgcn_global_load_lds width=16 (m93->m97 pattern:
//      no VGPR round-trip, 2 DMA insts/wave/stage). DMA needs a contiguous LDS
//      image, so prep writes ex_s PRE-SWIZZLED: k-block q of row r stored at
//      r*128 + (q ^ (r&7))*16 within each 8 KB stage image.
//  (b) Frag ds_reads use the same swizzle -> banks 4*(quad^(l15&7))+w = all 32
//      banks, 2-way aliasing (free, m136). R6/R7's LROW=72 pad was actually an
//      8-way conflict (any 16B-aligned row stride is >=8-way for 16 rows).
//  (c) ce/labels: per-stage register vector loads (L2-hot broadcasts), no LDS.
// Segment-sum stays the onehot-MFMA (zero atomics in-loop); relaxed global
// atomics at block end; separate log kernel (kernel boundary = ordering).
// Harness floor ~60 us (268 MB d_ws poison fill + restores) is untouchable.

#define NB      1024
#define NE      50000
#define NE_PAD  50176    // 98 chunks * 512
#define KD      64
#define NC      10
#define SROWS   64       // e-rows per stage (8 KB fp16 image)
#define NSTAGE  8        // 512 / SROWS

using half8   = __attribute__((ext_vector_type(8))) _Float16;  // 16x16x32 A/B frag (4 VGPRs)
using half4v  = __attribute__((ext_vector_type(4))) _Float16;  // 16x16x16 A/B frag (2 VGPRs)
using floatx4 = __attribute__((ext_vector_type(4))) float;

typedef const __attribute__((address_space(1))) void cgbl_void_t;
typedef __attribute__((address_space(3))) void lds_void_t;

__device__ __forceinline__ float softplus_f(float x) {
  return (x > 20.f) ? x : log1pf(__expf(x));
}

// ---------------------------------------------------------------------------
// prep: cast x/exemplars to fp16, cb = -beta*||x||^2, ce = -beta*||e||^2,
// padded labels, zero class_sims. 16 lanes/row, 16 rows/block, 3200 blocks.
// ex_s is written in DMA-ready swizzled stage images: chunk c, stage st, row r,
// k-block q (16 B) at byte ((c*8+st)*8192) + r*128 + (q^(r&7))*16.
// Pad rows [NE, NE_PAD): ex_s = 0, ce = -1e30 (=> sim exactly 0), label 0.
// ---------------------------------------------------------------------------
__global__ __launch_bounds__(256) void prep_kernel(
    const float* __restrict__ x, const float* __restrict__ ex,
    const int* __restrict__ labels, const float* __restrict__ beta_raw,
    _Float16* __restrict__ ex_s, float* __restrict__ ce,
    _Float16* __restrict__ x_h, float* __restrict__ cb,
    float* __restrict__ class_sims, int* __restrict__ lab_pad)
{
  const int tid = threadIdx.x;
  const int gid = blockIdx.x * 256 + tid;
  if (gid < NB * NC) class_sims[gid] = 0.f;

  const float beta = softplus_f(beta_raw[0]);

  const int row = blockIdx.x * 16 + (tid >> 4);  // 3200*16 = 51200 = NE_PAD + NB
  const int l16 = tid & 15;

  if (row < NE_PAD) {
    float4 v = make_float4(0.f, 0.f, 0.f, 0.f);
    if (row < NE) v = ((const float4*)ex)[row * 16 + l16];
    half4v hv = { (_Float16)v.x, (_Float16)v.y, (_Float16)v.z, (_Float16)v.w };
    // lane l16 holds bytes [l16*8, +8) of the fp16 row = half of k-block j=l16>>1
    const int c  = row >> 9;          // chunk
    const int st = (row >> 6) & 7;    // stage within chunk
    const int r  = row & 63;          // row within stage
    const int blk = (l16 >> 1) ^ (r & 7);
    char* dst = (char*)ex_s + (((size_t)(c * 8 + st)) << 13)
              + r * 128 + blk * 16 + (l16 & 1) * 8;
    *(half4v*)dst = hv;
    float s = v.x*v.x + v.y*v.y + v.z*v.z + v.w*v.w;
    #pragma unroll
    for (int m = 1; m < 16; m <<= 1) s += __shfl_xor(s, m, 64);
    if (l16 == 0) ce[row] = (row < NE) ? (-beta * s) : -1e30f;
    if (l16 == 1) lab_pad[row] = (row < NE) ? labels[row] : 0;
  } else {
    const int rx = row - NE_PAD;  // [0, NB)
    float4 v = ((const float4*)x)[rx * 16 + l16];
    half4v hv = { (_Float16)v.x, (_Float16)v.y, (_Float16)v.z, (_Float16)v.w };
    *(half4v*)(x_h + (size_t)rx * KD + l16 * 4) = hv;
    float s = v.x*v.x + v.y*v.y + v.z*v.z + v.w*v.w;
    #pragma unroll
    for (int m = 1; m < 16; m <<= 1) s += __shfl_xor(s, m, 64);
    if (l16 == 0) cb[rx] = -beta * s;
  }
}

// ---------------------------------------------------------------------------
// main: grid (16 btiles, 98 chunks), block = 4 waves, LDS = 2 x 8 KB stage bufs.
// Wave w owns batch cols [btile*64+16w, +16) (B-frags from x_h, loaded once).
// Per stage: DMA next stage into the other buffer (global_load_lds, 2 x 1 KB per
// wave), load ce/lab regs for this stage, compute 4 subtiles from swizzled LDS,
// one __syncthreads (drains DMA + fences buffer reuse).
// Subtile: ae from LDS at block quad^(l15&7) (2-way banks = free);
//   MFMA1 16x16x32 -> d[e][b]; p = exp(min(2*beta*d + cb + ce, 0)) fp16
//   (= the 16x16x16 B-frag); MFMA2 vs onehot labels -> acc[c][b] in AGPRs.
// Flush: one relaxed global fp32 atomic per (b, c<10) cell. NO fences.
// ---------------------------------------------------------------------------
__global__ __launch_bounds__(256) void main_kernel(
    const _Float16* __restrict__ ex_s, const float* __restrict__ ce,
    const _Float16* __restrict__ x_h, const float* __restrict__ cb,
    const int* __restrict__ lab_pad, const float* __restrict__ beta_raw,
    float* __restrict__ class_sims)
{
  __shared__ _Float16 Ah[2][SROWS * KD];   // 2 x 8192 B swizzled stage images

  const int tid  = threadIdx.x;
  const int wave = tid >> 6;
  const int lane = tid & 63;
  const int l15  = lane & 15;
  const int quad = lane >> 4;

  const int btile = blockIdx.x;
  const int chunk = blockIdx.y;
  const int e0    = chunk * 512;
  const int bm    = btile * 64 + wave * 16;

  const float beta = softplus_f(beta_raw[0]);
  const float s2 = 2.f * beta;

  // x B-frags: B[k=quad*8+j][n=l15] -> x_h row-major, loaded once per wave.
  const half8* xrow = (const half8*)(x_h + (size_t)(bm + l15) * KD);
  const half8 bx0 = xrow[quad];
  const half8 bx1 = xrow[quad + 4];
  const float cbl = cb[bm + l15];

  // DMA source/dest offsets: wave w moves bytes [w*1024,+1024) and [(w+4)*1024,+1024)
  // of each 8 KB stage image; per-lane global addr = base + lane*16, LDS dest is
  // wave-uniform (HW scatters lane i to lds+16*i).
  const char* gbase = (const char*)ex_s + (((size_t)chunk) << 16);  // chunk*8*8192

  // ---- prologue: DMA stage 0 -> buf 0 ----
  {
    const char* g = gbase;
    char* l = (char*)&Ah[0][0];
    __builtin_amdgcn_global_load_lds((cgbl_void_t*)(g + wave * 1024 + lane * 16),
                                     (lds_void_t*)(l + wave * 1024), 16, 0, 0);
    __builtin_amdgcn_global_load_lds((cgbl_void_t*)(g + (wave + 4) * 1024 + lane * 16),
                                     (lds_void_t*)(l + (wave + 4) * 1024), 16, 0, 0);
  }
  __syncthreads();

  floatx4 acc = {0.f, 0.f, 0.f, 0.f};

  #pragma unroll
  for (int st = 0; st < NSTAGE; ++st) {
    const int b = st & 1;

    // DMA stage st+1 into the other buffer (safe: it was last read in stage
    // st-1, and the barrier at the end of st-1 has been passed by all waves).
    if (st + 1 < NSTAGE) {
      const char* g = gbase + (size_t)(st + 1) * 8192;
      char* l = (char*)&Ah[1 - b][0];
      __builtin_amdgcn_global_load_lds((cgbl_void_t*)(g + wave * 1024 + lane * 16),
                                       (lds_void_t*)(l + wave * 1024), 16, 0, 0);
      __builtin_amdgcn_global_load_lds((cgbl_void_t*)(g + (wave + 4) * 1024 + lane * 16),
                                       (lds_void_t*)(l + (wave + 4) * 1024), 16, 0, 0);
    }

    // this stage's ce/labels: per-quad 16 B broadcast loads (L2-hot)
    float4 ce4s[4]; int4 lb4s[4];
    #pragma unroll
    for (int sub = 0; sub < 4; ++sub) {
      ce4s[sub] = *(const float4*)(ce + e0 + st * SROWS + sub * 16 + quad * 4);
      lb4s[sub] = *(const int4*)(lab_pad + e0 + st * SROWS + sub * 16 + quad * 4);
    }

    // compute 4 subtiles of 16 e-rows from swizzled LDS buf b
    #pragma unroll
    for (int sub = 0; sub < 4; ++sub) {
      const int rs = sub * 16 + l15;       // row within stage; rs&7 == l15&7
      const int sw = l15 & 7;
      const half8 ae0 = *(const half8*)(&Ah[b][rs * KD + ((quad ^ sw) * 8)]);
      const half8 ae1 = *(const half8*)(&Ah[b][rs * KD + (((quad + 4) ^ sw) * 8)]);

      floatx4 d = {0.f, 0.f, 0.f, 0.f};
      d = __builtin_amdgcn_mfma_f32_16x16x32_f16(ae0, bx0, d, 0, 0, 0);
      d = __builtin_amdgcn_mfma_f32_16x16x32_f16(ae1, bx1, d, 0, 0, 0);

      const float4 ce4 = ce4s[sub];
      const int4   lb4 = lb4s[sub];
      const float cef[4] = { ce4.x, ce4.y, ce4.z, ce4.w };
      half4v p;
      #pragma unroll
      for (int r = 0; r < 4; ++r) {
        const float t = fminf(fmaf(s2, d[r], cbl + cef[r]), 0.f);  // -beta*max(d2,0)
        p[r] = (_Float16)__expf(t);
      }

      half4v oh;
      oh[0] = (lb4.x == l15) ? (_Float16)1.f : (_Float16)0.f;
      oh[1] = (lb4.y == l15) ? (_Float16)1.f : (_Float16)0.f;
      oh[2] = (lb4.z == l15) ? (_Float16)1.f : (_Float16)0.f;
      oh[3] = (lb4.w == l15) ? (_Float16)1.f : (_Float16)0.f;

      acc = __builtin_amdgcn_mfma_f32_16x16x16f16(oh, p, acc, 0, 0, 0);
    }

    // end-of-stage barrier: fences buffer reuse and drains the st+1 DMA
    // (issued ~a full compute phase ago). Skipped after the last stage.
    if (st + 1 < NSTAGE) __syncthreads();
  }

  // acc: lane holds class_part[c = quad*4+r][b = l15] -> relaxed global atomics.
  #pragma unroll
  for (int r = 0; r < 4; ++r) {
    const int c = quad * 4 + r;
    if (c < NC) {
      __hip_atomic_fetch_add(&class_sims[(size_t)(bm + l15) * NC + c], acc[r],
                             __ATOMIC_RELAXED, __HIP_MEMORY_SCOPE_AGENT);
    }
  }
}

// ---------------------------------------------------------------------------
// finalize: logits = log(class_sims + eps). Kernel boundary orders the atomics.
// ---------------------------------------------------------------------------
__global__ __launch_bounds__(256) void log_kernel(
    const float* __restrict__ cs, float* __restrict__ out)
{
  const int i = blockIdx.x * 256 + threadIdx.x;
  if (i < NB * NC) out[i] = __logf(cs[i] + 1e-12f);
}

extern "C" void kernel_launch(void* const* d_in, const int* in_sizes, int n_in,
                              void* d_out, int out_size, void* d_ws, size_t ws_size,
                              hipStream_t stream)
{
  const float* x        = (const float*)d_in[0];
  const float* ex       = (const float*)d_in[1];
  const int*   labels   = (const int*)d_in[2];
  const float* beta_raw = (const float*)d_in[3];
  float* out = (float*)d_out;

  // Workspace layout (~7.0 MB total):
  char* ws = (char*)d_ws;
  _Float16* ex_s       = (_Float16*)ws;             // 50176*64*2 = 6,422,528 B
  float*    ce         = (float*)(ws + 6422528);    //   200,704 B
  _Float16* x_h        = (_Float16*)(ws + 6623232); //   131,072 B
  float*    cb         = (float*)(ws + 6754304);    //     4,096 B
  float*    class_sims = (float*)(ws + 6758400);    //    40,960 B
  int*      lab_pad    = (int*)(ws + 6799360);      //   200,704 B  (end: 7,000,064)

  prep_kernel<<<3200, 256, 0, stream>>>(x, ex, labels, beta_raw,
                                        ex_s, ce, x_h, cb, class_sims, lab_pad);
  dim3 g(16, 98);
  main_kernel<<<g, 256, 0, stream>>>(ex_s, ce, x_h, cb, lab_pad, beta_raw, class_sims);
  log_kernel<<<40, 256, 0, stream>>>(class_sims, out);
}

// Round 9
// 100.091 us; speedup vs baseline: 1.1035x; 1.1035x over previous
//
#include <hip/hip_runtime.h>

// ExemplarNoAttention: logits[b,c] = log( sum_{e: label[e]==c} exp(-beta*d2[b,e]) + eps )
// d2[b,e] = ||x_b||^2 + ||e_e||^2 - 2<x_b,e_e>, clamped >= 0; beta = softplus(beta_raw).
//
// Round 9 = R6 verbatim (best measured: 102.6 us; LDS double-buffered register
// staging) with ONE change: the 1M-device-atomic flush (98-way contention on a
// 40 KB hot array; WRITE_SIZE showed ~16 MB of memory-side RMW traffic = 16 B
// per atomic) is replaced by contention-free private partial stores:
//   main block (btile,chunk) -> part[chunk][ (btile*64+row)*10 + c ]  (640 floats,
//   coalesced, every cell written exactly once -> no zeroing, deterministic).
// log_kernel becomes a reduce: thread bc sums part[k][bc] over k=0..97 (fully
// coalesced per k-pass, ~4 MB L2-hot) and applies log(.+eps).
// Harness floor ~60 us (268 MB d_ws poison fill + input restores) is untouchable.

#define NB      1024
#define NE      50000
#define NE_PAD  50176    // 98 chunks * 512
#define NCHUNK  98
#define KD      64
#define NC      10
#define SROWS   64       // e-rows per stage
#define NSTAGE  8        // 512 / SROWS
#define LROW    72       // padded LDS row stride in halfs (144 B)

using half8   = __attribute__((ext_vector_type(8))) _Float16;  // 16x16x32 A/B frag (4 VGPRs)
using half4v  = __attribute__((ext_vector_type(4))) _Float16;  // 16x16x16 A/B frag (2 VGPRs)
using floatx4 = __attribute__((ext_vector_type(4))) float;

__device__ __forceinline__ float softplus_f(float x) {
  return (x > 20.f) ? x : log1pf(__expf(x));
}

// ---------------------------------------------------------------------------
// prep: cast x/exemplars to fp16, cb = -beta*||x||^2, ce = -beta*||e||^2,
// padded labels. 16 lanes/row, 16 rows/block, 3200 blocks.
// Pad rows [NE, NE_PAD): ex_h = 0, ce = -1e30 (=> sim exactly 0), label 0.
// ---------------------------------------------------------------------------
__global__ __launch_bounds__(256) void prep_kernel(
    const float* __restrict__ x, const float* __restrict__ ex,
    const int* __restrict__ labels, const float* __restrict__ beta_raw,
    _Float16* __restrict__ ex_h, float* __restrict__ ce,
    _Float16* __restrict__ x_h, float* __restrict__ cb,
    int* __restrict__ lab_pad)
{
  const int tid = threadIdx.x;
  const float beta = softplus_f(beta_raw[0]);

  const int row = blockIdx.x * 16 + (tid >> 4);  // 3200*16 = 51200 = NE_PAD + NB
  const int l16 = tid & 15;

  if (row < NE_PAD) {
    float4 v = make_float4(0.f, 0.f, 0.f, 0.f);
    if (row < NE) v = ((const float4*)ex)[row * 16 + l16];
    half4v hv = { (_Float16)v.x, (_Float16)v.y, (_Float16)v.z, (_Float16)v.w };
    *(half4v*)(ex_h + (size_t)row * KD + l16 * 4) = hv;
    float s = v.x*v.x + v.y*v.y + v.z*v.z + v.w*v.w;
    #pragma unroll
    for (int m = 1; m < 16; m <<= 1) s += __shfl_xor(s, m, 64);
    if (l16 == 0) ce[row] = (row < NE) ? (-beta * s) : -1e30f;
    if (l16 == 1) lab_pad[row] = (row < NE) ? labels[row] : 0;
  } else {
    const int rx = row - NE_PAD;  // [0, NB)
    float4 v = ((const float4*)x)[rx * 16 + l16];
    half4v hv = { (_Float16)v.x, (_Float16)v.y, (_Float16)v.z, (_Float16)v.w };
    *(half4v*)(x_h + (size_t)rx * KD + l16 * 4) = hv;
    float s = v.x*v.x + v.y*v.y + v.z*v.z + v.w*v.w;
    #pragma unroll
    for (int m = 1; m < 16; m <<= 1) s += __shfl_xor(s, m, 64);
    if (l16 == 0) cb[rx] = -beta * s;
  }
}

// ---------------------------------------------------------------------------
// main: grid (16 btiles, 98 chunks), block = 4 waves. Wave w owns batch cols
// [btile*64+16w, +16) (B-frags from x_h, loaded once). Per stage (64 e-rows):
//   prefetch next stage global->regs, compute 4 subtiles from LDS buf,
//   barrier, write regs->other buf, barrier.  (R6 structure, unchanged.)
// Subtile: MFMA1 16x16x32 -> d[e][b]; p = exp(min(2*beta*d + cb + ce, 0)) fp16
//   (= 16x16x16 B-frag); MFMA2 vs onehot labels -> acc[c][b] in AGPRs.
// Flush (CHANGED): plain coalesced stores of the block's 640-float partial into
//   part[chunk][(bm+l15)*10 + c] -- zero atomics, zero contention.
// ---------------------------------------------------------------------------
__global__ __launch_bounds__(256) void main_kernel(
    const _Float16* __restrict__ ex_h, const float* __restrict__ ce,
    const _Float16* __restrict__ x_h, const float* __restrict__ cb,
    const int* __restrict__ lab_pad, const float* __restrict__ beta_raw,
    float* __restrict__ part)
{
  __shared__ _Float16 Ah[2][SROWS * LROW];
  __shared__ float    Ce[2][SROWS];
  __shared__ int      Lb[2][SROWS];

  const int tid  = threadIdx.x;
  const int wave = tid >> 6;
  const int lane = tid & 63;
  const int l15  = lane & 15;
  const int quad = lane >> 4;

  const int btile = blockIdx.x;
  const int chunk = blockIdx.y;
  const int e0    = chunk * 512;
  const int bm    = btile * 64 + wave * 16;

  const float beta = softplus_f(beta_raw[0]);
  const float s2 = 2.f * beta;

  // x B-frags: B[k=quad*8+j][n=l15] -> x_h row-major, loaded once per wave.
  const half8* xrow = (const half8*)(x_h + (size_t)(bm + l15) * KD);
  const half8 bx0 = xrow[quad];
  const half8 bx1 = xrow[quad + 4];
  const float cbl = cb[bm + l15];

  // stage-load lane constants: thread t moves 32 B of row (t>>2), halfs [(t&3)*16..)
  const int srow = tid >> 2;
  const int scol = tid & 3;
  const _Float16* gsrc = ex_h + (size_t)(e0 + srow) * KD + scol * 16;
  const int lofs = srow * LROW + scol * 16;

  // ---- prologue: stage 0 global -> regs -> LDS buf 0 ----
  half8 pr0 = *(const half8*)(gsrc);
  half8 pr1 = *(const half8*)(gsrc + 8);
  float prc = 0.f; int prl = 0;
  if (wave == 0) prc = ce[e0 + lane];
  if (wave == 1) prl = lab_pad[e0 + lane];

  *(half8*)(&Ah[0][lofs])     = pr0;
  *(half8*)(&Ah[0][lofs + 8]) = pr1;
  if (wave == 0) Ce[0][lane] = prc;
  if (wave == 1) Lb[0][lane] = prl;
  __syncthreads();

  floatx4 acc = {0.f, 0.f, 0.f, 0.f};

  for (int st = 0; st < NSTAGE; ++st) {
    const int b = st & 1;

    // prefetch next stage into registers (vmcnt chain, independent of ds_reads)
    if (st + 1 < NSTAGE) {
      const _Float16* g = gsrc + (size_t)(st + 1) * SROWS * KD;
      pr0 = *(const half8*)(g);
      pr1 = *(const half8*)(g + 8);
      if (wave == 0) prc = ce[e0 + (st + 1) * SROWS + lane];
      if (wave == 1) prl = lab_pad[e0 + (st + 1) * SROWS + lane];
    }

    // compute 4 subtiles of 16 e-rows from LDS buf b
    #pragma unroll
    for (int sub = 0; sub < 4; ++sub) {
      const int abase = (sub * 16 + l15) * LROW + quad * 8;
      const half8 ae0 = *(const half8*)(&Ah[b][abase]);
      const half8 ae1 = *(const half8*)(&Ah[b][abase + 32]);
      const float4 ce4 = *(const float4*)(&Ce[b][sub * 16 + quad * 4]);
      const int4   lb4 = *(const int4*)(&Lb[b][sub * 16 + quad * 4]);

      floatx4 d = {0.f, 0.f, 0.f, 0.f};
      d = __builtin_amdgcn_mfma_f32_16x16x32_f16(ae0, bx0, d, 0, 0, 0);
      d = __builtin_amdgcn_mfma_f32_16x16x32_f16(ae1, bx1, d, 0, 0, 0);

      const float cef[4] = { ce4.x, ce4.y, ce4.z, ce4.w };
      half4v p;
      #pragma unroll
      for (int r = 0; r < 4; ++r) {
        const float t = fminf(fmaf(s2, d[r], cbl + cef[r]), 0.f);  // -beta*max(d2,0)
        p[r] = (_Float16)__expf(t);
      }

      half4v oh;
      oh[0] = (lb4.x == l15) ? (_Float16)1.f : (_Float16)0.f;
      oh[1] = (lb4.y == l15) ? (_Float16)1.f : (_Float16)0.f;
      oh[2] = (lb4.z == l15) ? (_Float16)1.f : (_Float16)0.f;
      oh[3] = (lb4.w == l15) ? (_Float16)1.f : (_Float16)0.f;

      acc = __builtin_amdgcn_mfma_f32_16x16x16f16(oh, p, acc, 0, 0, 0);
    }

    if (st + 1 < NSTAGE) {
      __syncthreads();
      const int nb = (st + 1) & 1;
      *(half8*)(&Ah[nb][lofs])     = pr0;
      *(half8*)(&Ah[nb][lofs + 8]) = pr1;
      if (wave == 0) Ce[nb][lane] = prc;
      if (wave == 1) Lb[nb][lane] = prl;
      __syncthreads();
    }
  }

  // Flush: acc holds class_part[c = quad*4+r][b = l15]. Private per-chunk slice,
  // plain stores, zero contention (each cell written by exactly one block).
  float* dst = part + (size_t)chunk * (NB * NC);
  #pragma unroll
  for (int r = 0; r < 4; ++r) {
    const int c = quad * 4 + r;
    if (c < NC) {
      dst[(bm + l15) * NC + c] = acc[r];
    }
  }
}

// ---------------------------------------------------------------------------
// reduce+finalize: out[bc] = log( sum_k part[k][bc] + eps ). Thread bc reads
// part[k][bc] -- consecutive threads hit consecutive addresses (coalesced);
// ~4 MB total, L2/L3-hot. Fixed summation order -> deterministic.
// ---------------------------------------------------------------------------
__global__ __launch_bounds__(256) void reduce_kernel(
    const float* __restrict__ part, float* __restrict__ out)
{
  const int bc = blockIdx.x * 256 + threadIdx.x;
  if (bc < NB * NC) {
    float s = 0.f;
    #pragma unroll 7
    for (int k = 0; k < NCHUNK; ++k) s += part[(size_t)k * (NB * NC) + bc];
    out[bc] = __logf(s + 1e-12f);
  }
}

extern "C" void kernel_launch(void* const* d_in, const int* in_sizes, int n_in,
                              void* d_out, int out_size, void* d_ws, size_t ws_size,
                              hipStream_t stream)
{
  const float* x        = (const float*)d_in[0];
  const float* ex       = (const float*)d_in[1];
  const int*   labels   = (const int*)d_in[2];
  const float* beta_raw = (const float*)d_in[3];
  float* out = (float*)d_out;

  // Workspace layout (~10.97 MB total):
  char* ws = (char*)d_ws;
  _Float16* ex_h    = (_Float16*)ws;             // 50176*64*2 = 6,422,528 B
  float*    ce      = (float*)(ws + 6422528);    //   200,704 B
  _Float16* x_h     = (_Float16*)(ws + 6623232); //   131,072 B
  float*    cb      = (float*)(ws + 6754304);    //     4,096 B
  int*      lab_pad = (int*)(ws + 6758400);      //   200,704 B
  float*    part    = (float*)(ws + 6959104);    // 98*10240*4 = 4,014,080 B (end: 10,973,184)

  prep_kernel<<<3200, 256, 0, stream>>>(x, ex, labels, beta_raw,
                                        ex_h, ce, x_h, cb, lab_pad);
  dim3 g(16, 98);
  main_kernel<<<g, 256, 0, stream>>>(ex_h, ce, x_h, cb, lab_pad, beta_raw, part);
  reduce_kernel<<<40, 256, 0, stream>>>(part, out);
}